// Round 12
// baseline (2580.746 us; speedup 1.0000x reference)
//
#include <hip/hip_runtime.h>
#include <cstdio>

typedef __attribute__((ext_vector_type(8))) short short8;
typedef __attribute__((ext_vector_type(4))) float f32x4;
typedef unsigned long long u64;

#define MFMA16(a,b,c) __builtin_amdgcn_mfma_f32_16x16x32_bf16((a),(b),(c),0,0,0)
#define LOAD_SYS(p)    __hip_atomic_load((p), __ATOMIC_RELAXED, __HIP_MEMORY_SCOPE_SYSTEM)
#define STORE_SYS(p,v) __hip_atomic_store((p), (v), __ATOMIC_RELAXED, __HIP_MEMORY_SCOPE_SYSTEM)

typedef __attribute__((address_space(1))) unsigned AS1U;
typedef __attribute__((address_space(3))) unsigned AS3U;

// workspace layout (bytes). 32 row-groups of 16 rows; tiles are 16KB.
constexpr size_t CNT_OFF = 0;                            // 32 groups * 128B counter lines
constexpr size_t HB_OFF  = 8192;                         // 2 * 32 * 16KB = 1MB
constexpr size_t PK1_OFF = HB_OFF + 1048576;             // Wh1 pack, 2MB
constexpr size_t PK2_OFF = PK1_OFF + 2097152;            // Wh2 pack, 2MB
constexpr size_t PKX_OFF = PK2_OFF + 2097152;            // Wx2 pack, 2MB
constexpr size_t SEQ_OFF = PKX_OFF + 2097152;            // seq1: 32 * 200 * 16KB (~100MB)
constexpr size_t WS_NEED = SEQ_OFF + 32ul * 200 * 16384; // ~112.2 MB (same as R11)

__device__ __forceinline__ short f2bf(float f) {
  union { float f; unsigned u; } v; v.f = f;
  unsigned r = v.u + 0x7fffu + ((v.u >> 16) & 1u);
  return (short)(r >> 16);
}
__device__ __forceinline__ float bf2f(short s) {
  union { float f; unsigned u; } v; v.u = ((unsigned)(unsigned short)s) << 16;
  return v.f;
}
__device__ __forceinline__ float sigm(float x)   { return 1.f / (1.f + __expf(-x)); }
__device__ __forceinline__ float tanh_f(float x) { return 1.f - 2.f / (1.f + __expf(2.f * x)); }

// Pack W[512][2048] fp32 (K x N) into MFMA B-fragment order:
// frag (nf,kf): lane l, elem e holds B[k = kf*32 + (l>>4)*8 + e][n = nf*16 + (l&15)]
__global__ void pack_w(const float* __restrict__ wh1, const float* __restrict__ wh2,
                       const float* __restrict__ wx2, unsigned char* __restrict__ ws)
{
  int tid = blockIdx.x * 256 + threadIdx.x;   // 3 * 65536 threads
  int m   = tid >> 16;
  int rem = tid & 65535;
  int k   = rem >> 7;     // 0..511
  int nf  = rem & 127;    // 0..127
  const float* W = (m == 0) ? wh1 : (m == 1) ? wh2 : wx2;
  short* dst = (short*)(ws + ((m == 0) ? PK1_OFF : (m == 1) ? PK2_OFF : PKX_OFF));
  int kf = k >> 5, sub = (k >> 3) & 3, e = k & 7;
  int base = ((nf * 16 + kf) * 64 + sub * 16) * 8 + e;
  const float* src = W + (size_t)k * 2048 + nf * 16;
#pragma unroll
  for (int c = 0; c < 16; ++c) dst[base + c * 8] = f2bf(src[c]);
}

// stage one 16KB tile LLC->LDS (4 glds per wave, linear both sides)
__device__ __forceinline__ void stage16k(const char* g, char* l, int w, int lane) {
#pragma unroll
  for (int i = 0; i < 4; ++i)
    __builtin_amdgcn_global_load_lds(
        (const AS1U*)(g + (w * 4 + i) * 1024 + lane * 16),
        (AS3U*)(l + (w * 4 + i) * 1024), 16, 0, 17 /* sc0|sc1 */);
}

#define LGKM_BAR() do { \
  asm volatile("s_waitcnt lgkmcnt(0)" ::: "memory"); \
  __builtin_amdgcn_s_barrier(); \
  __builtin_amdgcn_sched_barrier(0); } while (0)

// One diagonal-fused superstep for one group: L1 step s + L2 step s-1.
// Tiles tA (=h1_{s-1}) and tB (=h2_{s-2}) must be fully staged & drained by caller.
__device__ __forceinline__ void phase_step(
    int s, int tid, int lane, int w, int g0, int cf,
    const short8* tA, const short8* tB,
    const short8 (&wh1f)[2][16], const short8 (&wh2f)[2][16],
    const short8 (&wxhi)[2][8], const short8 (&bwx)[4][2][8][64],
    float (&zl1)[16][132], float (&zl2)[16][132],
    unsigned short (&ht1)[16][36], unsigned short (&ht2)[16][36],
    const float* xg, const float (&wx1v)[4], const float (&b1v)[4], const float (&b2v)[4],
    float (&c1)[2], float (&c2)[2],
    u64* seqG, u64* hbG0, u64* hbG1,
    int pr, int pq, int bq, unsigned* cnt)
{
  f32x4 a1[2], a2[2];
#pragma unroll
  for (int Gl = 0; Gl < 2; ++Gl) { f32x4 z = {0.f,0.f,0.f,0.f}; a1[Gl] = z; a2[Gl] = z; }

  if (s >= 1) {
#pragma unroll
    for (int kf = 0; kf < 16; ++kf) {
      short8 a = tA[kf * 64 + lane];
#pragma unroll
      for (int Gl = 0; Gl < 2; ++Gl) {
        if (s < 200) a1[Gl] = MFMA16(a, wh1f[Gl][kf], a1[Gl]);
        short8 bxf = (kf < 8) ? bwx[w][Gl][kf][lane] : wxhi[Gl][kf - 8];
        a2[Gl] = MFMA16(a, bxf, a2[Gl]);
      }
    }
  }
  if (s >= 2) {
#pragma unroll
    for (int kf = 0; kf < 16; ++kf) {
      short8 b = tB[kf * 64 + lane];
#pragma unroll
      for (int Gl = 0; Gl < 2; ++Gl)
        a2[Gl] = MFMA16(b, wh2f[Gl][kf], a2[Gl]);
    }
  }

  // scatter pre-activations (zero when MFMA skipped: matches h_{-1}=0 semantics)
  {
    int orow = (lane >> 4) * 4, oc = cf * 16 + (lane & 15);
#pragma unroll
    for (int Gl = 0; Gl < 2; ++Gl) {
      int cc = (g0 + Gl) * 32 + oc;
#pragma unroll
      for (int r4 = 0; r4 < 4; ++r4) {
        if (s >= 0 && s < 200)  zl1[orow + r4][cc] = a1[Gl][r4];
        if (s >= 1 && s <= 200) zl2[orow + r4][cc] = a2[Gl][r4];
      }
    }
  }
  LGKM_BAR();   // zl ready

  // gates: thread owns hcol, rows rq*2, rq*2+1
  {
    int hcol = tid & 31, rq = tid >> 5;
#pragma unroll
    for (int i = 0; i < 2; ++i) {
      int row = rq * 2 + i;
      if (s >= 0 && s < 200) {
        float x  = xg[row * 200 + s];
        float z0 = zl1[row][hcol]       + fmaf(x, wx1v[0], b1v[0]);
        float z1 = zl1[row][32 + hcol]  + fmaf(x, wx1v[1], b1v[1]);
        float z2 = zl1[row][64 + hcol]  + fmaf(x, wx1v[2], b1v[2]);
        float z3 = zl1[row][96 + hcol]  + fmaf(x, wx1v[3], b1v[3]);
        float cv = sigm(z1) * c1[i] + sigm(z0) * tanh_f(z2);
        c1[i] = cv;
        ht1[row][hcol] = (unsigned short)f2bf(sigm(z3) * tanh_f(cv));
      }
      if (s >= 1 && s <= 200) {
        float z0 = zl2[row][hcol]       + b2v[0];
        float z1 = zl2[row][32 + hcol]  + b2v[1];
        float z2 = zl2[row][64 + hcol]  + b2v[2];
        float z3 = zl2[row][96 + hcol]  + b2v[3];
        float cv = sigm(z1) * c2[i] + sigm(z0) * tanh_f(z2);
        c2[i] = cv;
        ht2[row][hcol] = (unsigned short)f2bf(sigm(z3) * tanh_f(cv));
      }
    }
  }
  LGKM_BAR();   // ht ready

  if (tid < 128) {
    if (s >= 0 && s < 200)
      STORE_SYS(seqG + (size_t)s * 2048 + bq, *(const u64*)&ht1[pr][pq * 4]);
    if (s >= 1 && s <= 200)
      STORE_SYS(((((s + 1) & 1) ? hbG1 : hbG0) + bq), *(const u64*)&ht2[pr][pq * 4]);
  }
  __syncthreads();   // drains vmcnt(0): our stores AND the other group's stage loads
  if (tid == 0 && s >= 0 && s <= 200)
    __hip_atomic_fetch_add(cnt, 1u, __ATOMIC_RELAXED, __HIP_MEMORY_SCOPE_SYSTEM);
}

// 256 WGs; WG (p, wj) serves groups A=2p, B=2p+1; owns h-cols [wj*32, wj*32+32).
__global__ __launch_bounds__(256, 1) void lstm_main(
    const float* __restrict__ inp, const float* __restrict__ Wx1,
    const float* __restrict__ b1,  const float* __restrict__ b2,
    const float* __restrict__ Wfc, const float* __restrict__ bfc,
    unsigned char* __restrict__ ws, float* __restrict__ out)
{
  __shared__ short8 ldsAA[1024], ldsBA[1024];   // group A tiles (seq, hb), 32KB
  __shared__ short8 ldsAB[1024], ldsBB[1024];   // group B tiles, 32KB
  __shared__ short8 bwx[4][2][8][64];           // Wx2 kf<8 per wave, 64KB
  __shared__ float  zl1[16][132], zl2[16][132]; // pre-act exchange, 16.5KB
  __shared__ unsigned short ht1[16][36], ht2[16][36];
  __shared__ float  red[256];

  const int tid  = threadIdx.x;
  const int blk  = blockIdx.x;
  const int p    = blk >> 4;     // pair index 0..15
  const int wj   = blk & 15;     // h-col block
  const int grA  = 2 * p, grB = 2 * p + 1;
  const int w    = tid >> 6;
  const int lane = tid & 63;
  const int g0   = (w >> 1) << 1;
  const int cf   = w & 1;

  unsigned* cntA = (unsigned*)(ws + CNT_OFF) + grA * 32;   // 128B apart
  unsigned* cntB = (unsigned*)(ws + CNT_OFF) + grB * 32;
  u64* hbA0 = (u64*)(ws + HB_OFF + (size_t)(0 * 32 + grA) * 16384);
  u64* hbA1 = (u64*)(ws + HB_OFF + (size_t)(1 * 32 + grA) * 16384);
  u64* hbB0 = (u64*)(ws + HB_OFF + (size_t)(0 * 32 + grB) * 16384);
  u64* hbB1 = (u64*)(ws + HB_OFF + (size_t)(1 * 32 + grB) * 16384);
  const short8* pk1 = (const short8*)(ws + PK1_OFF);
  const short8* pk2 = (const short8*)(ws + PK2_OFF);
  const short8* pkx = (const short8*)(ws + PKX_OFF);
  u64* seqA = (u64*)(ws + SEQ_OFF + (size_t)grA * 200 * 16384);
  u64* seqB = (u64*)(ws + SEQ_OFF + (size_t)grB * 200 * 16384);

  // B-fragments: Wh1, Wh2 in VGPRs; Wx2 kf<8 -> LDS, kf>=8 -> VGPRs
  short8 wh1f[2][16], wh2f[2][16], wxhi[2][8];
#pragma unroll
  for (int Gl = 0; Gl < 2; ++Gl) {
    int nf = (g0 + Gl) * 32 + wj * 2 + cf;
#pragma unroll
    for (int kf = 0; kf < 16; ++kf) {
      wh1f[Gl][kf] = pk1[(nf * 16 + kf) * 64 + lane];
      wh2f[Gl][kf] = pk2[(nf * 16 + kf) * 64 + lane];
    }
#pragma unroll
    for (int kf = 0; kf < 8; ++kf)
      bwx[w][Gl][kf][lane] = pkx[(nf * 16 + kf) * 64 + lane];
#pragma unroll
    for (int kf = 8; kf < 16; ++kf)
      wxhi[Gl][kf - 8] = pkx[(nf * 16 + kf) * 64 + lane];
  }

  // gate constants for this thread's z-column
  const int hcol = tid & 31;
  const int jcol = wj * 32 + hcol;
  float wx1v[4], b1v[4], b2v[4];
#pragma unroll
  for (int G = 0; G < 4; ++G) {
    wx1v[G] = Wx1[G * 512 + jcol];
    b1v[G]  = b1[G * 512 + jcol];
    b2v[G]  = b2[G * 512 + jcol];
  }
  const float* xgA = inp + (size_t)(grA * 16) * 200;
  const float* xgB = inp + (size_t)(grB * 16) * 200;

  // pack-thread mapping (tid<128): row pr, 4 cols at pc0
  const int pr = (tid & 127) >> 3, pq = tid & 7;
  const int pc0 = wj * 32 + pq * 4;
  const int bq = (((pc0 >> 5) * 64 + ((pc0 >> 3) & 3) * 16 + pr) * 8 + (pc0 & 7)) >> 2;

  float cA1[2] = {0.f, 0.f}, cA2[2] = {0.f, 0.f};
  float cB1[2] = {0.f, 0.f}, cB2[2] = {0.f, 0.f};

  __syncthreads();   // bwx staged

#pragma unroll 1
  for (int r = 0; r <= 201; ++r) {
    // ---- P1: group-A readiness (step r needs all posts of step r-1) ----
    if (r >= 1 && r <= 200) {
      if (tid < 64) {
        while ((int)LOAD_SYS(cntA) < 16 * r) __builtin_amdgcn_s_sleep(1);
        asm volatile("" ::: "memory");
      }
    }
    __syncthreads();

    // ---- P2: issue A-stage (async; completes during P3) ----
    if (r >= 1 && r <= 200)
      stage16k((const char*)seqA + (size_t)(r - 1) * 16384, (char*)ldsAA, w, lane);
    if (r >= 2 && r <= 200)
      stage16k((const char*)((r & 1) ? hbA1 : hbA0), (char*)ldsBA, w, lane);

    // ---- P3: compute B step r-1 (tiles staged last round, drained) ----
    phase_step(r - 1, tid, lane, w, g0, cf, ldsAB, ldsBB,
               wh1f, wh2f, wxhi, bwx, zl1, zl2, ht1, ht2,
               xgB, wx1v, b1v, b2v, cB1, cB2, seqB, hbB0, hbB1, pr, pq, bq, cntB);

    // ---- P4: group-B readiness ----
    if (r >= 1 && r <= 200) {
      if (tid < 64) {
        while ((int)LOAD_SYS(cntB) < 16 * r) __builtin_amdgcn_s_sleep(1);
        asm volatile("" ::: "memory");
      }
    }
    __syncthreads();

    // ---- P5: issue B-stage (completes during P6) ----
    if (r >= 1 && r <= 200)
      stage16k((const char*)seqB + (size_t)(r - 1) * 16384, (char*)ldsAB, w, lane);
    if (r >= 2 && r <= 200)
      stage16k((const char*)((r & 1) ? hbB1 : hbB0), (char*)ldsBB, w, lane);

    // ---- P6: compute A step r ----
    phase_step(r, tid, lane, w, g0, cf, ldsAA, ldsBA,
               wh1f, wh2f, wxhi, bwx, zl1, zl2, ht1, ht2,
               xgA, wx1v, b1v, b2v, cA1, cA2, seqA, hbA0, hbA1, pr, pq, bq, cntA);
  }

  // ---- final FC: logits = h2_199 @ Wfc + bfc (hb1 of each group) ----
  if (wj == 0) {
    if (tid < 64) {
      while ((int)LOAD_SYS(cntA) < 16 * 201) __builtin_amdgcn_s_sleep(1);
      while ((int)LOAD_SYS(cntB) < 16 * 201) __builtin_amdgcn_s_sleep(1);
      asm volatile("" ::: "memory");
    }
    __syncthreads();

    int r2 = tid >> 3, q = tid & 7;
    int row = r2 & 15;
    const u64* h2 = (r2 < 16) ? hbA1 : hbB1;
    float sum = 0.f;
#pragma unroll
    for (int c = 0; c < 8; ++c) {
      int k0 = q * 64 + c * 8;
      int bq2 = ((k0 >> 5) * 64 + ((k0 >> 3) & 3) * 16 + row) * 2;
      union { u64 u[2]; unsigned short ss[8]; } cv;
      cv.u[0] = LOAD_SYS((u64*)h2 + bq2);
      cv.u[1] = LOAD_SYS((u64*)h2 + bq2 + 1);
#pragma unroll
      for (int e = 0; e < 8; ++e)
        sum = fmaf(bf2f((short)cv.ss[e]), Wfc[k0 + e], sum);
    }
    red[tid] = sum;
    __syncthreads();
    if (q == 0) {
      float o = bfc[0];
#pragma unroll
      for (int j = 0; j < 8; ++j) o += red[r2 * 8 + j];
      int gr = (r2 < 16) ? grA : grB;
      out[gr * 16 + row] = o;
    }
  }
}

extern "C" void kernel_launch(void* const* d_in, const int* in_sizes, int n_in,
                              void* d_out, int out_size, void* d_ws, size_t ws_size,
                              hipStream_t stream)
{
  if (ws_size < WS_NEED) {
    fprintf(stderr, "kernel_launch: ws_size %zu < needed %zu\n", ws_size, WS_NEED);
    return;
  }
  const float* inp = (const float*)d_in[0];
  const float* Wx1 = (const float*)d_in[1];
  const float* Wh1 = (const float*)d_in[2];
  const float* b1  = (const float*)d_in[3];
  const float* Wx2 = (const float*)d_in[4];
  const float* Wh2 = (const float*)d_in[5];
  const float* b2  = (const float*)d_in[6];
  const float* Wfc = (const float*)d_in[7];
  const float* bfc = (const float*)d_in[8];
  unsigned char* ws = (unsigned char*)d_ws;

  hipMemsetAsync(ws, 0, 8192, stream);                        // counters
  pack_w<<<768, 256, 0, stream>>>(Wh1, Wh2, Wx2, ws);
  lstm_main<<<256, 256, 0, stream>>>(inp, Wx1, b1, b2, Wfc, bfc, ws, (float*)d_out);
}

// Round 13
// 2403.079 us; speedup vs baseline: 1.0739x; 1.0739x over previous
//
#include <hip/hip_runtime.h>
#include <cstdio>

typedef __attribute__((ext_vector_type(8))) short short8;
typedef __attribute__((ext_vector_type(4))) float f32x4;
typedef unsigned long long u64;

#define MFMA16(a,b,c) __builtin_amdgcn_mfma_f32_16x16x32_bf16((a),(b),(c),0,0,0)
#define LOAD_SYS(p)    __hip_atomic_load((p), __ATOMIC_RELAXED, __HIP_MEMORY_SCOPE_SYSTEM)
#define STORE_SYS(p,v) __hip_atomic_store((p), (v), __ATOMIC_RELAXED, __HIP_MEMORY_SCOPE_SYSTEM)

typedef __attribute__((address_space(1))) unsigned AS1U;
typedef __attribute__((address_space(3))) unsigned AS3U;

// workspace layout (bytes). 32 row-groups of 16 rows; tiles are 16KB.
constexpr size_t CNT_OFF = 0;                            // 32 groups * 128B flag lines
constexpr size_t HB_OFF  = 8192;                         // 2 * 32 * 16KB = 1MB
constexpr size_t PK1_OFF = HB_OFF + 1048576;             // Wh1 pack, 2MB
constexpr size_t PK2_OFF = PK1_OFF + 2097152;            // Wh2 pack, 2MB
constexpr size_t PKX_OFF = PK2_OFF + 2097152;            // Wx2 pack, 2MB
constexpr size_t SEQ_OFF = PKX_OFF + 2097152;            // seq1: 32 * 200 * 16KB (~100MB)
constexpr size_t WS_NEED = SEQ_OFF + 32ul * 200 * 16384; // ~112.2 MB

__device__ __forceinline__ short f2bf(float f) {
  union { float f; unsigned u; } v; v.f = f;
  unsigned r = v.u + 0x7fffu + ((v.u >> 16) & 1u);
  return (short)(r >> 16);
}
__device__ __forceinline__ float bf2f(short s) {
  union { float f; unsigned u; } v; v.u = ((unsigned)(unsigned short)s) << 16;
  return v.f;
}
__device__ __forceinline__ float sigm(float x)   { return 1.f / (1.f + __expf(-x)); }
__device__ __forceinline__ float tanh_f(float x) { return 1.f - 2.f / (1.f + __expf(2.f * x)); }

// Pack W[512][2048] fp32 (K x N) into MFMA B-fragment order:
// frag (nf,kf): lane l, elem e holds B[k = kf*32 + (l>>4)*8 + e][n = nf*16 + (l&15)]
__global__ void pack_w(const float* __restrict__ wh1, const float* __restrict__ wh2,
                       const float* __restrict__ wx2, unsigned char* __restrict__ ws)
{
  int tid = blockIdx.x * 256 + threadIdx.x;   // 3 * 65536 threads
  int m   = tid >> 16;
  int rem = tid & 65535;
  int k   = rem >> 7;     // 0..511
  int nf  = rem & 127;    // 0..127
  const float* W = (m == 0) ? wh1 : (m == 1) ? wh2 : wx2;
  short* dst = (short*)(ws + ((m == 0) ? PK1_OFF : (m == 1) ? PK2_OFF : PKX_OFF));
  int kf = k >> 5, sub = (k >> 3) & 3, e = k & 7;
  int base = ((nf * 16 + kf) * 64 + sub * 16) * 8 + e;
  const float* src = W + (size_t)k * 2048 + nf * 16;
#pragma unroll
  for (int c = 0; c < 16; ++c) dst[base + c * 8] = f2bf(src[c]);
}

// stage one 16KB tile LLC->LDS (4 glds per wave, linear both sides)
__device__ __forceinline__ void stage16k(const char* g, char* l, int w, int lane) {
#pragma unroll
  for (int i = 0; i < 4; ++i)
    __builtin_amdgcn_global_load_lds(
        (const AS1U*)(g + (w * 4 + i) * 1024 + lane * 16),
        (AS3U*)(l + (w * 4 + i) * 1024), 16, 0, 17 /* sc0|sc1 */);
}

#define LGKM_BAR() do { \
  asm volatile("s_waitcnt lgkmcnt(0)" ::: "memory"); \
  __builtin_amdgcn_s_barrier(); \
  __builtin_amdgcn_sched_barrier(0); } while (0)

// One diagonal-fused superstep for one group: L1 step s + L2 step s-1.
// Entry: drains this group's async stage (vmcnt) + barrier, then computes.
// Exit: posts per-WG flag fl[wj] = s+1 (after store-drain barrier).
__device__ __forceinline__ void phase_step(
    int s, int tid, int lane, int w, int g0, int cf,
    const short8* tA, const short8* tB,
    const short8 (&wh1f)[2][16], const short8 (&wh2f)[2][16],
    const short8 (&wxhi)[2][8], const short8 (&bwx)[4][2][8][64],
    float (&zl1)[16][132], float (&zl2)[16][132],
    unsigned short (&ht1)[16][36], unsigned short (&ht2)[16][36],
    const float* xg, const float (&wx1v)[4], const float (&b1v)[4], const float (&b2v)[4],
    float (&c1)[2], float (&c2)[2],
    u64* seqG, u64* hbG0, u64* hbG1,
    int pr, int pq, int bq, unsigned* fl, int wj)
{
  // entry drain: our stage loads (issued earlier) -> LDS visible to all waves
  asm volatile("s_waitcnt vmcnt(0)" ::: "memory");
  __builtin_amdgcn_sched_barrier(0);
  __builtin_amdgcn_s_barrier();
  __builtin_amdgcn_sched_barrier(0);

  f32x4 a1[2], a2[2];
#pragma unroll
  for (int Gl = 0; Gl < 2; ++Gl) { f32x4 z = {0.f,0.f,0.f,0.f}; a1[Gl] = z; a2[Gl] = z; }

  if (s >= 1 && s <= 200) {
#pragma unroll
    for (int kf = 0; kf < 16; ++kf) {
      short8 a = tA[kf * 64 + lane];
#pragma unroll
      for (int Gl = 0; Gl < 2; ++Gl) {
        if (s < 200) a1[Gl] = MFMA16(a, wh1f[Gl][kf], a1[Gl]);
        short8 bxf = (kf < 8) ? bwx[w][Gl][kf][lane] : wxhi[Gl][kf - 8];
        a2[Gl] = MFMA16(a, bxf, a2[Gl]);
      }
    }
  }
  if (s >= 2 && s <= 200) {
#pragma unroll
    for (int kf = 0; kf < 16; ++kf) {
      short8 b = tB[kf * 64 + lane];
#pragma unroll
      for (int Gl = 0; Gl < 2; ++Gl)
        a2[Gl] = MFMA16(b, wh2f[Gl][kf], a2[Gl]);
    }
  }

  // scatter pre-activations
  {
    int orow = (lane >> 4) * 4, oc = cf * 16 + (lane & 15);
#pragma unroll
    for (int Gl = 0; Gl < 2; ++Gl) {
      int cc = (g0 + Gl) * 32 + oc;
#pragma unroll
      for (int r4 = 0; r4 < 4; ++r4) {
        if (s >= 0 && s < 200)  zl1[orow + r4][cc] = a1[Gl][r4];
        if (s >= 1 && s <= 200) zl2[orow + r4][cc] = a2[Gl][r4];
      }
    }
  }
  LGKM_BAR();   // zl ready

  // gates: thread owns hcol, rows rq*2, rq*2+1
  {
    int hcol = tid & 31, rq = tid >> 5;
#pragma unroll
    for (int i = 0; i < 2; ++i) {
      int row = rq * 2 + i;
      if (s >= 0 && s < 200) {
        float x  = xg[row * 200 + s];
        float z0 = zl1[row][hcol]       + fmaf(x, wx1v[0], b1v[0]);
        float z1 = zl1[row][32 + hcol]  + fmaf(x, wx1v[1], b1v[1]);
        float z2 = zl1[row][64 + hcol]  + fmaf(x, wx1v[2], b1v[2]);
        float z3 = zl1[row][96 + hcol]  + fmaf(x, wx1v[3], b1v[3]);
        float cv = sigm(z1) * c1[i] + sigm(z0) * tanh_f(z2);
        c1[i] = cv;
        ht1[row][hcol] = (unsigned short)f2bf(sigm(z3) * tanh_f(cv));
      }
      if (s >= 1 && s <= 200) {
        float z0 = zl2[row][hcol]       + b2v[0];
        float z1 = zl2[row][32 + hcol]  + b2v[1];
        float z2 = zl2[row][64 + hcol]  + b2v[2];
        float z3 = zl2[row][96 + hcol]  + b2v[3];
        float cv = sigm(z1) * c2[i] + sigm(z0) * tanh_f(z2);
        c2[i] = cv;
        ht2[row][hcol] = (unsigned short)f2bf(sigm(z3) * tanh_f(cv));
      }
    }
  }
  LGKM_BAR();   // ht ready

  if (tid < 128) {
    if (s >= 0 && s < 200)
      STORE_SYS(seqG + (size_t)s * 2048 + bq, *(const u64*)&ht1[pr][pq * 4]);
    if (s >= 1 && s <= 200)
      STORE_SYS(((((s + 1) & 1) ? hbG1 : hbG0) + bq), *(const u64*)&ht2[pr][pq * 4]);
  }
  __syncthreads();   // drains vmcnt(0): all waves' stores acked before post
  if (tid == 0 && s >= 0 && s <= 200)
    STORE_SYS(&fl[wj], (unsigned)(s + 1));
}

// poll: all 16 WGs of a group posted >= r (64 lanes, 4x redundant reads; no RMW)
__device__ __forceinline__ void poll_group(const unsigned* fl, unsigned r, int tid) {
  if (tid < 64) {
    const unsigned* fp = &fl[tid & 15];
    while (1) {
      unsigned v = LOAD_SYS((unsigned*)fp);
      if (__all((int)(v >= r))) break;
      __builtin_amdgcn_s_sleep(1);
    }
    asm volatile("" ::: "memory");
  }
  __syncthreads();
}

// 256 WGs; WG (p, wj) serves groups A=2p, B=2p+1; owns h-cols [wj*32, wj*32+32).
// Round r: [computeB(r-1) | pollA(r) | stageA(r) | computeA(r) | pollB(r) | stageB(r)]
// -> every poll has ~half a round of slack after its posts; stages drain at compute entry.
__global__ __launch_bounds__(256, 1) void lstm_main(
    const float* __restrict__ inp, const float* __restrict__ Wx1,
    const float* __restrict__ b1,  const float* __restrict__ b2,
    const float* __restrict__ Wfc, const float* __restrict__ bfc,
    unsigned char* __restrict__ ws, float* __restrict__ out)
{
  __shared__ short8 ldsAA[1024], ldsBA[1024];   // group A tiles (seq, hb), 32KB
  __shared__ short8 ldsAB[1024], ldsBB[1024];   // group B tiles, 32KB
  __shared__ short8 bwx[4][2][8][64];           // Wx2 kf<8 per wave, 64KB
  __shared__ float  zl1[16][132], zl2[16][132]; // pre-act exchange, 16.5KB
  __shared__ unsigned short ht1[16][36], ht2[16][36];
  __shared__ float  red[256];

  const int tid  = threadIdx.x;
  const int blk  = blockIdx.x;
  const int p    = blk >> 4;     // pair index 0..15
  const int wj   = blk & 15;     // h-col block
  const int grA  = 2 * p, grB = 2 * p + 1;
  const int w    = tid >> 6;
  const int lane = tid & 63;
  const int g0   = (w >> 1) << 1;
  const int cf   = w & 1;

  unsigned* flA = (unsigned*)(ws + CNT_OFF) + grA * 32;   // 128B lines
  unsigned* flB = (unsigned*)(ws + CNT_OFF) + grB * 32;
  u64* hbA0 = (u64*)(ws + HB_OFF + (size_t)(0 * 32 + grA) * 16384);
  u64* hbA1 = (u64*)(ws + HB_OFF + (size_t)(1 * 32 + grA) * 16384);
  u64* hbB0 = (u64*)(ws + HB_OFF + (size_t)(0 * 32 + grB) * 16384);
  u64* hbB1 = (u64*)(ws + HB_OFF + (size_t)(1 * 32 + grB) * 16384);
  const short8* pk1 = (const short8*)(ws + PK1_OFF);
  const short8* pk2 = (const short8*)(ws + PK2_OFF);
  const short8* pkx = (const short8*)(ws + PKX_OFF);
  u64* seqA = (u64*)(ws + SEQ_OFF + (size_t)grA * 200 * 16384);
  u64* seqB = (u64*)(ws + SEQ_OFF + (size_t)grB * 200 * 16384);

  // B-fragments: Wh1, Wh2 in VGPRs; Wx2 kf<8 -> LDS, kf>=8 -> VGPRs
  short8 wh1f[2][16], wh2f[2][16], wxhi[2][8];
#pragma unroll
  for (int Gl = 0; Gl < 2; ++Gl) {
    int nf = (g0 + Gl) * 32 + wj * 2 + cf;
#pragma unroll
    for (int kf = 0; kf < 16; ++kf) {
      wh1f[Gl][kf] = pk1[(nf * 16 + kf) * 64 + lane];
      wh2f[Gl][kf] = pk2[(nf * 16 + kf) * 64 + lane];
    }
#pragma unroll
    for (int kf = 0; kf < 8; ++kf)
      bwx[w][Gl][kf][lane] = pkx[(nf * 16 + kf) * 64 + lane];
#pragma unroll
    for (int kf = 8; kf < 16; ++kf)
      wxhi[Gl][kf - 8] = pkx[(nf * 16 + kf) * 64 + lane];
  }

  // gate constants for this thread's z-column
  const int hcol = tid & 31;
  const int jcol = wj * 32 + hcol;
  float wx1v[4], b1v[4], b2v[4];
#pragma unroll
  for (int G = 0; G < 4; ++G) {
    wx1v[G] = Wx1[G * 512 + jcol];
    b1v[G]  = b1[G * 512 + jcol];
    b2v[G]  = b2[G * 512 + jcol];
  }
  const float* xgA = inp + (size_t)(grA * 16) * 200;
  const float* xgB = inp + (size_t)(grB * 16) * 200;

  // pack-thread mapping (tid<128): row pr, 4 cols at pc0
  const int pr = (tid & 127) >> 3, pq = tid & 7;
  const int pc0 = wj * 32 + pq * 4;
  const int bq = (((pc0 >> 5) * 64 + ((pc0 >> 3) & 3) * 16 + pr) * 8 + (pc0 & 7)) >> 2;

  float cA1[2] = {0.f, 0.f}, cA2[2] = {0.f, 0.f};
  float cB1[2] = {0.f, 0.f}, cB2[2] = {0.f, 0.f};

  __syncthreads();   // bwx staged

#pragma unroll 1
  for (int r = 0; r <= 201; ++r) {
    // ---- op1: compute B step r-1 (tiles staged at op6 of round r-1) ----
    phase_step(r - 1, tid, lane, w, g0, cf, ldsAB, ldsBB,
               wh1f, wh2f, wxhi, bwx, zl1, zl2, ht1, ht2,
               xgB, wx1v, b1v, b2v, cB1, cB2, seqB, hbB0, hbB1, pr, pq, bq, flB, wj);

    // ---- op2: poll A (posts were ~half a round ago) ----
    if (r >= 1 && r <= 200) poll_group(flA, (unsigned)r, tid);

    // ---- op3: issue A-stage (drained at computeA entry) ----
    if (r >= 1 && r <= 200)
      stage16k((const char*)seqA + (size_t)(r - 1) * 16384, (char*)ldsAA, w, lane);
    if (r >= 2 && r <= 200)
      stage16k((const char*)((r & 1) ? hbA1 : hbA0), (char*)ldsBA, w, lane);

    // ---- op4: compute A step r ----
    phase_step(r, tid, lane, w, g0, cf, ldsAA, ldsBA,
               wh1f, wh2f, wxhi, bwx, zl1, zl2, ht1, ht2,
               xgA, wx1v, b1v, b2v, cA1, cA2, seqA, hbA0, hbA1, pr, pq, bq, flA, wj);

    // ---- op5: poll B (posts were at op1 of this round) ----
    if (r >= 1 && r <= 200) poll_group(flB, (unsigned)r, tid);

    // ---- op6: issue B-stage (drained at next round's computeB entry) ----
    if (r >= 1 && r <= 200)
      stage16k((const char*)seqB + (size_t)(r - 1) * 16384, (char*)ldsAB, w, lane);
    if (r >= 2 && r <= 200)
      stage16k((const char*)((r & 1) ? hbB1 : hbB0), (char*)ldsBB, w, lane);
  }

  // ---- final FC: logits = h2_199 @ Wfc + bfc (hb1 of each group) ----
  if (wj == 0) {
    if (tid < 64) {
      const unsigned* fa = &flA[tid & 15];
      while (1) {
        unsigned v = LOAD_SYS((unsigned*)fa);
        if (__all((int)(v >= 201u))) break;
        __builtin_amdgcn_s_sleep(1);
      }
      const unsigned* fb = &flB[tid & 15];
      while (1) {
        unsigned v = LOAD_SYS((unsigned*)fb);
        if (__all((int)(v >= 201u))) break;
        __builtin_amdgcn_s_sleep(1);
      }
      asm volatile("" ::: "memory");
    }
    __syncthreads();

    int r2 = tid >> 3, q = tid & 7;
    int row = r2 & 15;
    const u64* h2 = (r2 < 16) ? hbA1 : hbB1;
    float sum = 0.f;
#pragma unroll
    for (int c = 0; c < 8; ++c) {
      int k0 = q * 64 + c * 8;
      int bq2 = ((k0 >> 5) * 64 + ((k0 >> 3) & 3) * 16 + row) * 2;
      union { u64 u[2]; unsigned short ss[8]; } cv;
      cv.u[0] = LOAD_SYS((u64*)h2 + bq2);
      cv.u[1] = LOAD_SYS((u64*)h2 + bq2 + 1);
#pragma unroll
      for (int e = 0; e < 8; ++e)
        sum = fmaf(bf2f((short)cv.ss[e]), Wfc[k0 + e], sum);
    }
    red[tid] = sum;
    __syncthreads();
    if (q == 0) {
      float o = bfc[0];
#pragma unroll
      for (int j = 0; j < 8; ++j) o += red[r2 * 8 + j];
      int gr = (r2 < 16) ? grA : grB;
      out[gr * 16 + row] = o;
    }
  }
}

extern "C" void kernel_launch(void* const* d_in, const int* in_sizes, int n_in,
                              void* d_out, int out_size, void* d_ws, size_t ws_size,
                              hipStream_t stream)
{
  if (ws_size < WS_NEED) {
    fprintf(stderr, "kernel_launch: ws_size %zu < needed %zu\n", ws_size, WS_NEED);
    return;
  }
  const float* inp = (const float*)d_in[0];
  const float* Wx1 = (const float*)d_in[1];
  const float* Wh1 = (const float*)d_in[2];
  const float* b1  = (const float*)d_in[3];
  const float* Wx2 = (const float*)d_in[4];
  const float* Wh2 = (const float*)d_in[5];
  const float* b2  = (const float*)d_in[6];
  const float* Wfc = (const float*)d_in[7];
  const float* bfc = (const float*)d_in[8];
  unsigned char* ws = (unsigned char*)d_ws;

  hipMemsetAsync(ws, 0, 8192, stream);                        // flags
  pack_w<<<768, 256, 0, stream>>>(Wh1, Wh2, Wx2, ws);
  lstm_main<<<256, 256, 0, stream>>>(inp, Wx1, b1, b2, Wfc, bfc, ws, (float*)d_out);
}